// Round 7
// baseline (1012.426 us; speedup 1.0000x reference)
//
#include <hip/hip_runtime.h>

typedef _Float16 half8 __attribute__((ext_vector_type(8)));
typedef _Float16 half4v __attribute__((ext_vector_type(4)));
typedef float floatx4 __attribute__((ext_vector_type(4)));

// ---------------------------------------------------------------------------
// R7 MEGAKERNEL: entire 6-layer decoder in ONE persistent kernel.
// 512 blocks x 256 threads, 2 blocks/CU guaranteed by __launch_bounds__(256,2)
// -> all blocks co-resident -> software grid barrier is safe.
// Same dataflow as R5/R6: conv -> fp32 partial slabs -> fused reduce (ReLU +
// fp16 + padded channels-last) -> next conv. Stride-2 convs use balanced 27
// (class,tap) pairs. 10 grid barriers replace 11 dispatch boundaries.
// ---------------------------------------------------------------------------

#define GRID 512

__device__ __forceinline__ void sync_lds() {
  asm volatile("s_waitcnt lgkmcnt(0)\n\ts_barrier" ::: "memory");
}

__device__ __forceinline__ void grid_sync(unsigned* bar, unsigned* gen) {
  __syncthreads();  // drains each thread's outstanding stores (vmcnt)
  if (threadIdx.x == 0) {
    __threadfence();  // agent-scope release: writeback this XCD's L2
    unsigned g = __hip_atomic_load(gen, __ATOMIC_RELAXED,
                                   __HIP_MEMORY_SCOPE_AGENT);
    unsigned a = __hip_atomic_fetch_add(bar, 1u, __ATOMIC_ACQ_REL,
                                        __HIP_MEMORY_SCOPE_AGENT);
    if (a + 1u == (unsigned)GRID) {
      __hip_atomic_store(bar, 0u, __ATOMIC_RELAXED, __HIP_MEMORY_SCOPE_AGENT);
      __hip_atomic_store(gen, g + 1u, __ATOMIC_RELEASE,
                         __HIP_MEMORY_SCOPE_AGENT);
    } else {
      while (__hip_atomic_load(gen, __ATOMIC_ACQUIRE,
                               __HIP_MEMORY_SCOPE_AGENT) == g)
        __builtin_amdgcn_s_sleep(2);
    }
    __threadfence();  // agent-scope acquire: invalidate L1/L2 before reads
  }
  __syncthreads();
}

struct ConvSmem {
  _Float16 A[2 * 128 * 40];  // [buf][row<=128][KP=40]
  _Float16 B[2 * 64 * 40];   // [buf][row<=64][KP=40]
};
union SMem {
  ConvSmem c;
  float w6[864];
};

// One MFMA implicit-GEMM tile (KB=32). SMODE: 0 = stride1 tap-groups,
// 1 = stride2 (class,tap) pairs, 2 = stride2 class-loop.
// STORE_MODE: 2 = fp16 ReLU store into padded (S+2)^3, 3 = fp32 partial slab.
template <int CICHUNK, int CIN, int COUT, int NTILE, int TZ, int SOUTU,
          int PS, int SMODE, int TAPG, int STORE_MODE>
__device__ __forceinline__ void conv_tile(int bx, int by, int bz,
                                          const _Float16* __restrict__ P,
                                          const float* __restrict__ W,
                                          void* __restrict__ Optr,
                                          _Float16* __restrict__ smA,
                                          _Float16* __restrict__ smB) {
  constexpr int M = TZ * 16;
  constexpr bool S2 = (SMODE != 0);
  constexpr int MTZ = SOUTU / TZ;
  constexpr int MTXY = SOUTU / 4;
  constexpr int MT3 = MTZ * MTXY * MTXY;
  constexpr int KB = 32, KP = 40;
  constexpr int KBI = CICHUNK / KB;
  constexpr int NCI = CIN / CICHUNK;
  constexpr int S = S2 ? 2 * SOUTU : SOUTU;
  constexpr int WM = (M == 128) ? 4 : 2;
  constexpr int NSUB = (WM == 4) ? (NTILE / 16) : (NTILE / 32);
  constexpr int BJ = KB * NTILE / 256;  // 8 (NTILE=64) or 4 (NTILE=32)
  constexpr size_t U3 = (size_t)SOUTU * SOUTU * SOUTU;
  constexpr int ABUF = 128 * KP;
  constexpr int BBUF = 64 * KP;

  int cls = 0, tap0 = 0, cig = bz, jspl = 0;
  int p_toz = 0, p_toy = 0, p_tox = 0, p_wtap = 0;
  if (SMODE == 0) {
    const int tg = cig / NCI;
    cig -= tg * NCI;
    tap0 = tg * TAPG;
    jspl = bz;
  } else if (SMODE == 1) {
    const int p = bx / MT3;
    bx -= p * MT3;
    jspl = p * NCI + cig;
    cls = (p >= 8) + (p >= 12) + (p >= 16) + (p >= 18) + (p >= 22) +
          (p >= 24) + (p >= 26);
    const int pf = cls == 0 ? 0 : cls == 1 ? 8 : cls == 2 ? 12
                 : cls == 3 ? 16 : cls == 4 ? 18 : cls == 5 ? 22
                 : cls == 6 ? 24 : 26;
    const int tl = p - pf;
    const int lz = (cls >> 2) & 1, ly = (cls >> 1) & 1, lx = cls & 1;
    const int shx = lx ? 0 : 1, shy = ly ? 0 : 1;
    const int iz = tl >> (shx + shy);
    const int rem = tl & ((1 << (shx + shy)) - 1);
    const int iy = rem >> shx;
    const int ix = rem & ((1 << shx) - 1);
    p_toz = lz ? 1 : iz;
    p_toy = ly ? 1 : iy;
    p_tox = lx ? 1 : ix;
    const int wz = lz ? 1 : 2 * iz, wy = ly ? 1 : 2 * iy, wx = lx ? 1 : 2 * ix;
    p_wtap = (wz * 3 + wy) * 3 + wx;
  } else {
    cls = bx / MT3;
    bx -= cls * MT3;
  }
  const int clz = (cls >> 2) & 1, cly = (cls >> 1) & 1, clx = cls & 1;

  const int u0z = (bx / (MTXY * MTXY)) * TZ;
  const int u0y = ((bx / MTXY) % MTXY) * 4;
  const int u0x = (bx % MTXY) * 4;
  const int n_base = by * NTILE;

  const int t = threadIdx.x;
  const int lane = t & 63;
  const int wave = t >> 6;

  const int skq = t & 3;
  const int sp = t >> 2;
  const int spx = sp & 3, spy = (sp >> 2) & 3, spz = sp >> 4;
  const int nB = t & (NTILE - 1);
  const int k0B = (t / NTILE) * BJ;
  const int m0w = (WM == 4) ? wave * 32 : (wave >> 1) * 32;
  const int n0w = (WM == 4) ? 0 : (wave & 1) * 32;
  const int fr = lane & 15;
  const int fq = lane >> 4;

  const int cz = S2 ? (clz ? 1 : 2) : 3;
  const int cy = S2 ? (cly ? 1 : 2) : 3;
  const int cx = S2 ? (clx ? 1 : 2) : 3;
  const int shx2 = clx ? 0 : 1, shy2 = cly ? 0 : 1;

  const int NIT = (SMODE == 2) ? cz * cy * cx * KBI
                               : (SMODE == 0 ? TAPG * KBI : KBI);

  floatx4 acc[2][NSUB];
#pragma unroll
  for (int i = 0; i < 2; i++)
#pragma unroll
    for (int s = 0; s < NSUB; s++) acc[i][s] = {0.f, 0.f, 0.f, 0.f};

  struct RS {
    half8 a0, a1;
    float b[BJ];
  };
  RS s0, s1;

  auto load_it = [&](int it, RS& R) {
    int tap, kb;
    if (SMODE == 1) { tap = 0; kb = it; }
    else if (KBI == 1) { tap = it; kb = 0; }
    else { tap = it / KBI; kb = it - tap * KBI; }
    int toz, toy, tox, wtap;
    if (SMODE == 1) {
      toz = p_toz; toy = p_toy; tox = p_tox; wtap = p_wtap;
    } else if (SMODE == 0) {
      const int tt = tap0 + tap;
      const int iz = tt / 9;
      const int rem = tt - iz * 9;
      const int iy = rem / 3;
      const int ix = rem - iy * 3;
      toz = iz; toy = iy; tox = ix;
      wtap = tt;
    } else {
      const int iz = tap >> (shx2 + shy2);
      const int rem = tap & ((1 << (shx2 + shy2)) - 1);
      const int iy = rem >> shx2;
      const int ix = rem & ((1 << shx2) - 1);
      toz = clz ? 1 : iz; toy = cly ? 1 : iy; tox = clx ? 1 : ix;
      const int wz = clz ? 1 : 2 * iz, wy = cly ? 1 : 2 * iy,
                wx = clx ? 1 : 2 * ix;
      wtap = (wz * 3 + wy) * 3 + wx;
    }
    const int kof0 = cig * CICHUNK + kb * KB;
    const size_t pb =
        ((size_t)(((u0z + toz + spz) * PS + (u0y + toy + spy)) * PS +
                  (u0x + tox + spx))) * CIN + kof0 + skq * 8;
    R.a0 = *(const half8*)(P + pb);
    if (M == 128) R.a1 = *(const half8*)(P + pb + (size_t)4 * PS * PS * CIN);
    const float* wb =
        W + ((size_t)wtap * CIN + kof0 + k0B) * COUT + n_base + nB;
#pragma unroll
    for (int j = 0; j < BJ; j++) R.b[j] = wb[(size_t)j * COUT];
  };

  auto stage = [&](int buf, RS& R) {
    *(half8*)&smA[buf * ABUF + sp * KP + skq * 8] = R.a0;
    if (M == 128) *(half8*)&smA[buf * ABUF + (sp + 64) * KP + skq * 8] = R.a1;
    if (BJ == 8) {
      half8 hb;
#pragma unroll
      for (int j = 0; j < 8; j++) hb[j] = (_Float16)R.b[j];
      *(half8*)&smB[buf * BBUF + nB * KP + k0B] = hb;
    } else {
      half4v hb;
#pragma unroll
      for (int j = 0; j < 4; j++) hb[j] = (_Float16)R.b[j];
      *(half4v*)&smB[buf * BBUF + nB * KP + k0B] = hb;
    }
  };

  auto mfma_step = [&](int buf) {
    const int ko = fq * 8;
    half8 a0 = *(const half8*)&smA[buf * ABUF + (m0w + fr) * KP + ko];
    half8 a1 = *(const half8*)&smA[buf * ABUF + (m0w + 16 + fr) * KP + ko];
#pragma unroll
    for (int s = 0; s < NSUB; s++) {
      half8 b = *(const half8*)&smB[buf * BBUF + (n0w + s * 16 + fr) * KP + ko];
      acc[0][s] =
          __builtin_amdgcn_mfma_f32_16x16x32_f16(a0, b, acc[0][s], 0, 0, 0);
      acc[1][s] =
          __builtin_amdgcn_mfma_f32_16x16x32_f16(a1, b, acc[1][s], 0, 0, 0);
    }
  };

  load_it(0, s0);
  if (NIT > 1) load_it(1, s1);
  stage(0, s0);
  sync_lds();
  for (int it = 0; it < NIT; ++it) {
    const int cb = it & 1;
    if (it + 2 < NIT) load_it(it + 2, cb ? s1 : s0);
    mfma_step(cb);
    if (it + 1 < NIT) stage(cb ^ 1, cb ? s0 : s1);
    sync_lds();
  }

#pragma unroll
  for (int i = 0; i < 2; i++) {
#pragma unroll
    for (int r = 0; r < 4; r++) {
      const int m = m0w + i * 16 + fq * 4 + r;
      const int mz = m >> 4, my = (m >> 2) & 3, mx = m & 3;
      if (STORE_MODE == 2) {
        const int oz = 2 * (u0z + mz) + clz;
        const int oy = 2 * (u0y + my) + cly;
        const int ox = 2 * (u0x + mx) + clx;
        _Float16* o = (_Float16*)Optr +
            ((size_t)(((oz + 1) * (S + 2) + (oy + 1)) * (S + 2) + (ox + 1))) *
                COUT + n_base + n0w;
#pragma unroll
        for (int s = 0; s < NSUB; s++)
          o[s * 16 + fr] = (_Float16)fmaxf(acc[i][s][r], 0.f);
      } else {
        const size_t pos =
            ((size_t)((u0z + mz) * SOUTU + (u0y + my))) * SOUTU + (u0x + mx);
        float* o = (float*)Optr + ((size_t)jspl * U3 + pos) * COUT + n_base +
                   n0w;
#pragma unroll
        for (int s = 0; s < NSUB; s++) o[s * 16 + fr] = acc[i][s][r];
      }
    }
  }
}

// Reduce partials -> ReLU -> fp16 -> padded next-layer input (grid-stride).
template <int POS, int COUT, int S2IN, int NSPL, int PS>
__device__ __forceinline__ void red_stage(const float* __restrict__ Pp,
                                          _Float16* __restrict__ P) {
  constexpr int C4 = COUT / 4;
  constexpr int TOT = PS * PS * PS * C4;
  constexpr size_t U3 = S2IN
      ? (size_t)(POS / 2) * (POS / 2) * (POS / 2)
      : (size_t)POS * POS * POS;
  for (int idx = blockIdx.x * 256 + threadIdx.x; idx < TOT;
       idx += GRID * 256) {
    const int co = (idx % C4) * 4;
    const int r = idx / C4;
    const int px = r % PS, py = (r / PS) % PS, pz = r / (PS * PS);
    const int ix = px - 1, iy = py - 1, iz = pz - 1;
    float4 s = make_float4(0.f, 0.f, 0.f, 0.f);
    if ((unsigned)ix < (unsigned)POS && (unsigned)iy < (unsigned)POS &&
        (unsigned)iz < (unsigned)POS) {
      int j0, j1;
      size_t upos;
      if (S2IN) {
        const int pf[8] = {0, 8, 12, 16, 18, 22, 24, 26};
        const int tc[8] = {8, 4, 4, 2, 4, 2, 2, 1};
        const int cls = ((iz & 1) << 2) | ((iy & 1) << 1) | (ix & 1);
        j0 = pf[cls] * NSPL;
        j1 = j0 + tc[cls] * NSPL;
        constexpr int U = POS / 2;
        upos = ((size_t)(iz >> 1) * U + (iy >> 1)) * U + (ix >> 1);
      } else {
        j0 = 0;
        j1 = NSPL;
        upos = ((size_t)iz * POS + iy) * POS + ix;
      }
      const float* base = Pp + upos * COUT + co;
      for (int j = j0; j < j1; j++) {
        float4 v = *(const float4*)(base + (size_t)j * U3 * COUT);
        s.x += v.x; s.y += v.y; s.z += v.z; s.w += v.w;
      }
    }
    half4v h;
    h[0] = (_Float16)fmaxf(s.x, 0.f);
    h[1] = (_Float16)fmaxf(s.y, 0.f);
    h[2] = (_Float16)fmaxf(s.z, 0.f);
    h[3] = (_Float16)fmaxf(s.w, 0.f);
    *(half4v*)(P + (size_t)idx * 4) = h;
  }
}

__global__ __launch_bounds__(256, 2) void mega_k(
    const float* __restrict__ x, const float* __restrict__ w1,
    const float* __restrict__ w2, const float* __restrict__ w3,
    const float* __restrict__ w4, const float* __restrict__ w5,
    const float* __restrict__ w6, float* __restrict__ out,
    float* __restrict__ ws) {
  __shared__ SMem sm;
  unsigned* bar = (unsigned*)ws;
  unsigned* gen = (unsigned*)ws + 32;
  float* Q1 = ws + 64;                       // 216*64*512   = 7077888
  float* Q2 = Q1 + 7077888;                  // 24*512*256   = 3145728
  float* Q3 = Q2 + 3145728;                  // 54*512*128   = 3538944
  float* Q4 = Q3 + 3538944;                  // 12*4096*64   = 3145728
  _Float16* P1 = (_Float16*)(Q4 + 3145728);  // 5^3 *1024 = 128000
  _Float16* P2 = P1 + 128000;                // 10^3*512  = 512000
  _Float16* P3 = P2 + 512000;                // 9^3 *256  = 186624
  _Float16* P4 = P3 + 186624;                // 18^3*128  = 746496
  _Float16* P5 = P4 + 746496;                // 17^3*64   = 314432
  _Float16* P6 = P5 + 314432;                // 34^3*32   = 1257728

  const int gtid = blockIdx.x * 256 + threadIdx.x;

  // S0: pad x -> P1 (channels-last, left-pad 1) and zero all of P6
  for (int idx = gtid; idx < 125 * 1024; idx += GRID * 256) {
    int c = idx & 1023;
    int r = idx >> 10;
    int px = r % 5, py = (r / 5) % 5, pz = r / 25;
    float v = 0.f;
    if (px >= 1 && py >= 1 && pz >= 1)
      v = x[c * 64 + (pz - 1) * 16 + (py - 1) * 4 + (px - 1)];
    P1[idx] = (_Float16)v;
  }
  {
    half8 z = {};
    for (int idx = gtid; idx < 157216; idx += GRID * 256)
      *(half8*)(P6 + (size_t)idx * 8) = z;
  }
  grid_sync(bar, gen);

  // S1: conv1 1024->512, 4^3->8^3, s2; tiles (27,8,8) = 1728
  for (int vt = blockIdx.x; vt < 1728; vt += GRID)
    conv_tile<128, 1024, 512, 64, 4, 4, 5, 1, 0, 3>(
        vt % 27, (vt / 27) & 7, vt / 216, P1, w1, Q1, sm.c.A, sm.c.B);
  grid_sync(bar, gen);

  // S2: red1 -> P2 (10^3 x 512)
  red_stage<8, 512, 1, 8, 10>(Q1, P2);
  grid_sync(bar, gen);

  // S3: conv2 512->256, 8^3, s1; tiles (4,4,24) = 384
  for (int vt = blockIdx.x; vt < 384; vt += GRID)
    conv_tile<64, 512, 256, 64, 8, 8, 10, 0, 9, 3>(
        vt & 3, (vt / 4) & 3, vt / 16, P2, w2, Q2, sm.c.A, sm.c.B);
  grid_sync(bar, gen);

  // S4: red2 -> P3 (9^3 x 256)
  red_stage<8, 256, 0, 24, 9>(Q2, P3);
  grid_sync(bar, gen);

  // S5: conv3 256->128, 8^3->16^3, s2; tiles (108,2,2) = 432
  for (int vt = blockIdx.x; vt < 432; vt += GRID)
    conv_tile<128, 256, 128, 64, 8, 8, 9, 1, 0, 3>(
        vt % 108, (vt / 108) & 1, vt / 216, P3, w3, Q3, sm.c.A, sm.c.B);
  grid_sync(bar, gen);

  // S6: red3 -> P4 (18^3 x 128)
  red_stage<16, 128, 1, 2, 18>(Q3, P4);
  grid_sync(bar, gen);

  // S7: conv4 128->64, 16^3, s1; tiles (32,1,12) = 384
  for (int vt = blockIdx.x; vt < 384; vt += GRID)
    conv_tile<32, 128, 64, 64, 8, 16, 18, 0, 9, 3>(
        vt & 31, 0, vt / 32, P4, w4, Q4, sm.c.A, sm.c.B);
  grid_sync(bar, gen);

  // S8: red4 -> P5 (17^3 x 64)
  red_stage<16, 64, 0, 12, 17>(Q4, P5);
  grid_sync(bar, gen);

  // S9: conv5 64->32, 16^3->32^3, s2 class-loop, fp16 ReLU -> padded P6
  for (int vt = blockIdx.x; vt < 256; vt += GRID)
    conv_tile<64, 64, 32, 32, 8, 16, 17, 2, 0, 2>(
        vt, 0, 0, P5, w5, P6, sm.c.A, sm.c.B);
  grid_sync(bar, gen);

  // S10: conv6 32->1, 32^3 (no ReLU)
  for (int i = threadIdx.x; i < 864; i += 256) sm.w6[i] = w6[i];
  __syncthreads();
  for (int idx = gtid; idx < 32768; idx += GRID * 256) {
    int xx = idx & 31, yy = (idx >> 5) & 31, zz = idx >> 10;
    float a = 0.f;
    for (int dz = 0; dz < 3; dz++)
      for (int dy = 0; dy < 3; dy++)
        for (int dx = 0; dx < 3; dx++) {
          const _Float16* p =
              P6 + (size_t)(((zz + dz) * 34 + (yy + dy)) * 34 + (xx + dx)) * 32;
          const float* ww = &sm.w6[((dz * 3 + dy) * 3 + dx) * 32];
#pragma unroll
          for (int c = 0; c < 32; c += 8) {
            half8 pv = *(const half8*)&p[c];
#pragma unroll
            for (int u = 0; u < 8; u++) a += (float)pv[u] * ww[c + u];
          }
        }
    out[idx] = a;
  }
}

extern "C" void kernel_launch(void* const* d_in, const int* in_sizes, int n_in,
                              void* d_out, int out_size, void* d_ws,
                              size_t ws_size, hipStream_t stream) {
  const float* x  = (const float*)d_in[0];
  const float* w1 = (const float*)d_in[1];
  const float* w2 = (const float*)d_in[2];
  const float* w3 = (const float*)d_in[3];
  const float* w4 = (const float*)d_in[4];
  const float* w5 = (const float*)d_in[5];
  const float* w6 = (const float*)d_in[6];

  // zero the barrier state (first 256 B of ws)
  hipMemsetAsync(d_ws, 0, 256, stream);
  mega_k<<<GRID, 256, 0, stream>>>(x, w1, w2, w3, w4, w5, w6, (float*)d_out,
                                   (float*)d_ws);

  (void)in_sizes; (void)n_in; (void)out_size; (void)ws_size;
}

// Round 8
// 373.408 us; speedup vs baseline: 2.7113x; 2.7113x over previous
//
#include <hip/hip_runtime.h>

typedef _Float16 half8 __attribute__((ext_vector_type(8)));
typedef _Float16 half4v __attribute__((ext_vector_type(4)));
typedef float floatx4 __attribute__((ext_vector_type(4)));

// ---------------------------------------------------------------------------
// R8 MEGAKERNEL, fixed grid barrier. R7's barrier polled with an ACQUIRE
// atomic load (per-poll buffer_inv = per-XCD L2 invalidation storm -> 90us
// per barrier). R8 polls RELAXED (agent-scope load reads the coherent point,
// no invalidation), with ONE release fence before arrival and ONE acquire
// fence after exit. Dataflow unchanged from R7 (numerically identical).
// ---------------------------------------------------------------------------

#define GRID 512

__device__ __forceinline__ void sync_lds() {
  asm volatile("s_waitcnt lgkmcnt(0)\n\ts_barrier" ::: "memory");
}

__device__ __forceinline__ void grid_sync(unsigned* bar, unsigned* gen) {
  __syncthreads();  // each wave drains its own vmcnt before arrival
  if (threadIdx.x == 0) {
    // one release fence: write back this XCD's L2 so stores are visible
    __builtin_amdgcn_fence(__ATOMIC_RELEASE, "agent");
    unsigned g = __hip_atomic_load(gen, __ATOMIC_RELAXED,
                                   __HIP_MEMORY_SCOPE_AGENT);
    unsigned a = __hip_atomic_fetch_add(bar, 1u, __ATOMIC_RELAXED,
                                        __HIP_MEMORY_SCOPE_AGENT);
    if (a + 1u == (unsigned)GRID) {
      __hip_atomic_store(bar, 0u, __ATOMIC_RELAXED, __HIP_MEMORY_SCOPE_AGENT);
      __hip_atomic_store(gen, g + 1u, __ATOMIC_RELAXED,
                         __HIP_MEMORY_SCOPE_AGENT);
    } else {
      // RELAXED poll: no per-iteration cache invalidation
      while (__hip_atomic_load(gen, __ATOMIC_RELAXED,
                               __HIP_MEMORY_SCOPE_AGENT) == g)
        __builtin_amdgcn_s_sleep(4);
    }
    // one acquire fence: invalidate L1/L2 once so we read others' data fresh
    __builtin_amdgcn_fence(__ATOMIC_ACQUIRE, "agent");
  }
  __syncthreads();
}

struct ConvSmem {
  _Float16 A[2 * 128 * 40];  // [buf][row<=128][KP=40]
  _Float16 B[2 * 64 * 40];   // [buf][row<=64][KP=40]
};
union SMem {
  ConvSmem c;
  float w6[864];
};

// One MFMA implicit-GEMM tile (KB=32). SMODE: 0 = stride1 tap-groups,
// 1 = stride2 (class,tap) pairs, 2 = stride2 class-loop.
// STORE_MODE: 2 = fp16 ReLU store into padded (S+2)^3, 3 = fp32 partial slab.
template <int CICHUNK, int CIN, int COUT, int NTILE, int TZ, int SOUTU,
          int PS, int SMODE, int TAPG, int STORE_MODE>
__device__ __forceinline__ void conv_tile(int bx, int by, int bz,
                                          const _Float16* __restrict__ P,
                                          const float* __restrict__ W,
                                          void* __restrict__ Optr,
                                          _Float16* __restrict__ smA,
                                          _Float16* __restrict__ smB) {
  constexpr int M = TZ * 16;
  constexpr bool S2 = (SMODE != 0);
  constexpr int MTZ = SOUTU / TZ;
  constexpr int MTXY = SOUTU / 4;
  constexpr int MT3 = MTZ * MTXY * MTXY;
  constexpr int KB = 32, KP = 40;
  constexpr int KBI = CICHUNK / KB;
  constexpr int NCI = CIN / CICHUNK;
  constexpr int S = S2 ? 2 * SOUTU : SOUTU;
  constexpr int WM = (M == 128) ? 4 : 2;
  constexpr int NSUB = (WM == 4) ? (NTILE / 16) : (NTILE / 32);
  constexpr int BJ = KB * NTILE / 256;  // 8 (NTILE=64) or 4 (NTILE=32)
  constexpr size_t U3 = (size_t)SOUTU * SOUTU * SOUTU;
  constexpr int ABUF = 128 * KP;
  constexpr int BBUF = 64 * KP;

  int cls = 0, tap0 = 0, cig = bz, jspl = 0;
  int p_toz = 0, p_toy = 0, p_tox = 0, p_wtap = 0;
  if (SMODE == 0) {
    const int tg = cig / NCI;
    cig -= tg * NCI;
    tap0 = tg * TAPG;
    jspl = bz;
  } else if (SMODE == 1) {
    const int p = bx / MT3;
    bx -= p * MT3;
    jspl = p * NCI + cig;
    cls = (p >= 8) + (p >= 12) + (p >= 16) + (p >= 18) + (p >= 22) +
          (p >= 24) + (p >= 26);
    const int pf = cls == 0 ? 0 : cls == 1 ? 8 : cls == 2 ? 12
                 : cls == 3 ? 16 : cls == 4 ? 18 : cls == 5 ? 22
                 : cls == 6 ? 24 : 26;
    const int tl = p - pf;
    const int lz = (cls >> 2) & 1, ly = (cls >> 1) & 1, lx = cls & 1;
    const int shx = lx ? 0 : 1, shy = ly ? 0 : 1;
    const int iz = tl >> (shx + shy);
    const int rem = tl & ((1 << (shx + shy)) - 1);
    const int iy = rem >> shx;
    const int ix = rem & ((1 << shx) - 1);
    p_toz = lz ? 1 : iz;
    p_toy = ly ? 1 : iy;
    p_tox = lx ? 1 : ix;
    const int wz = lz ? 1 : 2 * iz, wy = ly ? 1 : 2 * iy, wx = lx ? 1 : 2 * ix;
    p_wtap = (wz * 3 + wy) * 3 + wx;
  } else {
    cls = bx / MT3;
    bx -= cls * MT3;
  }
  const int clz = (cls >> 2) & 1, cly = (cls >> 1) & 1, clx = cls & 1;

  const int u0z = (bx / (MTXY * MTXY)) * TZ;
  const int u0y = ((bx / MTXY) % MTXY) * 4;
  const int u0x = (bx % MTXY) * 4;
  const int n_base = by * NTILE;

  const int t = threadIdx.x;
  const int lane = t & 63;
  const int wave = t >> 6;

  const int skq = t & 3;
  const int sp = t >> 2;
  const int spx = sp & 3, spy = (sp >> 2) & 3, spz = sp >> 4;
  const int nB = t & (NTILE - 1);
  const int k0B = (t / NTILE) * BJ;
  const int m0w = (WM == 4) ? wave * 32 : (wave >> 1) * 32;
  const int n0w = (WM == 4) ? 0 : (wave & 1) * 32;
  const int fr = lane & 15;
  const int fq = lane >> 4;

  const int cz = S2 ? (clz ? 1 : 2) : 3;
  const int cy = S2 ? (cly ? 1 : 2) : 3;
  const int cx = S2 ? (clx ? 1 : 2) : 3;
  const int shx2 = clx ? 0 : 1, shy2 = cly ? 0 : 1;

  const int NIT = (SMODE == 2) ? cz * cy * cx * KBI
                               : (SMODE == 0 ? TAPG * KBI : KBI);

  floatx4 acc[2][NSUB];
#pragma unroll
  for (int i = 0; i < 2; i++)
#pragma unroll
    for (int s = 0; s < NSUB; s++) acc[i][s] = {0.f, 0.f, 0.f, 0.f};

  struct RS {
    half8 a0, a1;
    float b[BJ];
  };
  RS s0, s1;

  auto load_it = [&](int it, RS& R) {
    int tap, kb;
    if (SMODE == 1) { tap = 0; kb = it; }
    else if (KBI == 1) { tap = it; kb = 0; }
    else { tap = it / KBI; kb = it - tap * KBI; }
    int toz, toy, tox, wtap;
    if (SMODE == 1) {
      toz = p_toz; toy = p_toy; tox = p_tox; wtap = p_wtap;
    } else if (SMODE == 0) {
      const int tt = tap0 + tap;
      const int iz = tt / 9;
      const int rem = tt - iz * 9;
      const int iy = rem / 3;
      const int ix = rem - iy * 3;
      toz = iz; toy = iy; tox = ix;
      wtap = tt;
    } else {
      const int iz = tap >> (shx2 + shy2);
      const int rem = tap & ((1 << (shx2 + shy2)) - 1);
      const int iy = rem >> shx2;
      const int ix = rem & ((1 << shx2) - 1);
      toz = clz ? 1 : iz; toy = cly ? 1 : iy; tox = clx ? 1 : ix;
      const int wz = clz ? 1 : 2 * iz, wy = cly ? 1 : 2 * iy,
                wx = clx ? 1 : 2 * ix;
      wtap = (wz * 3 + wy) * 3 + wx;
    }
    const int kof0 = cig * CICHUNK + kb * KB;
    const size_t pb =
        ((size_t)(((u0z + toz + spz) * PS + (u0y + toy + spy)) * PS +
                  (u0x + tox + spx))) * CIN + kof0 + skq * 8;
    R.a0 = *(const half8*)(P + pb);
    if (M == 128) R.a1 = *(const half8*)(P + pb + (size_t)4 * PS * PS * CIN);
    const float* wb =
        W + ((size_t)wtap * CIN + kof0 + k0B) * COUT + n_base + nB;
#pragma unroll
    for (int j = 0; j < BJ; j++) R.b[j] = wb[(size_t)j * COUT];
  };

  auto stage = [&](int buf, RS& R) {
    *(half8*)&smA[buf * ABUF + sp * KP + skq * 8] = R.a0;
    if (M == 128) *(half8*)&smA[buf * ABUF + (sp + 64) * KP + skq * 8] = R.a1;
    if (BJ == 8) {
      half8 hb;
#pragma unroll
      for (int j = 0; j < 8; j++) hb[j] = (_Float16)R.b[j];
      *(half8*)&smB[buf * BBUF + nB * KP + k0B] = hb;
    } else {
      half4v hb;
#pragma unroll
      for (int j = 0; j < 4; j++) hb[j] = (_Float16)R.b[j];
      *(half4v*)&smB[buf * BBUF + nB * KP + k0B] = hb;
    }
  };

  auto mfma_step = [&](int buf) {
    const int ko = fq * 8;
    half8 a0 = *(const half8*)&smA[buf * ABUF + (m0w + fr) * KP + ko];
    half8 a1 = *(const half8*)&smA[buf * ABUF + (m0w + 16 + fr) * KP + ko];
#pragma unroll
    for (int s = 0; s < NSUB; s++) {
      half8 b = *(const half8*)&smB[buf * BBUF + (n0w + s * 16 + fr) * KP + ko];
      acc[0][s] =
          __builtin_amdgcn_mfma_f32_16x16x32_f16(a0, b, acc[0][s], 0, 0, 0);
      acc[1][s] =
          __builtin_amdgcn_mfma_f32_16x16x32_f16(a1, b, acc[1][s], 0, 0, 0);
    }
  };

  load_it(0, s0);
  if (NIT > 1) load_it(1, s1);
  stage(0, s0);
  sync_lds();
  for (int it = 0; it < NIT; ++it) {
    const int cb = it & 1;
    if (it + 2 < NIT) load_it(it + 2, cb ? s1 : s0);
    mfma_step(cb);
    if (it + 1 < NIT) stage(cb ^ 1, cb ? s0 : s1);
    sync_lds();
  }

#pragma unroll
  for (int i = 0; i < 2; i++) {
#pragma unroll
    for (int r = 0; r < 4; r++) {
      const int m = m0w + i * 16 + fq * 4 + r;
      const int mz = m >> 4, my = (m >> 2) & 3, mx = m & 3;
      if (STORE_MODE == 2) {
        const int oz = 2 * (u0z + mz) + clz;
        const int oy = 2 * (u0y + my) + cly;
        const int ox = 2 * (u0x + mx) + clx;
        _Float16* o = (_Float16*)Optr +
            ((size_t)(((oz + 1) * (S + 2) + (oy + 1)) * (S + 2) + (ox + 1))) *
                COUT + n_base + n0w;
#pragma unroll
        for (int s = 0; s < NSUB; s++)
          o[s * 16 + fr] = (_Float16)fmaxf(acc[i][s][r], 0.f);
      } else {
        const size_t pos =
            ((size_t)((u0z + mz) * SOUTU + (u0y + my))) * SOUTU + (u0x + mx);
        float* o = (float*)Optr + ((size_t)jspl * U3 + pos) * COUT + n_base +
                   n0w;
#pragma unroll
        for (int s = 0; s < NSUB; s++) o[s * 16 + fr] = acc[i][s][r];
      }
    }
  }
}

// Reduce partials -> ReLU -> fp16 -> padded next-layer input (grid-stride).
template <int POS, int COUT, int S2IN, int NSPL, int PS>
__device__ __forceinline__ void red_stage(const float* __restrict__ Pp,
                                          _Float16* __restrict__ P) {
  constexpr int C4 = COUT / 4;
  constexpr int TOT = PS * PS * PS * C4;
  constexpr size_t U3 = S2IN
      ? (size_t)(POS / 2) * (POS / 2) * (POS / 2)
      : (size_t)POS * POS * POS;
  for (int idx = blockIdx.x * 256 + threadIdx.x; idx < TOT;
       idx += GRID * 256) {
    const int co = (idx % C4) * 4;
    const int r = idx / C4;
    const int px = r % PS, py = (r / PS) % PS, pz = r / (PS * PS);
    const int ix = px - 1, iy = py - 1, iz = pz - 1;
    float4 s = make_float4(0.f, 0.f, 0.f, 0.f);
    if ((unsigned)ix < (unsigned)POS && (unsigned)iy < (unsigned)POS &&
        (unsigned)iz < (unsigned)POS) {
      int j0, j1;
      size_t upos;
      if (S2IN) {
        const int pf[8] = {0, 8, 12, 16, 18, 22, 24, 26};
        const int tc[8] = {8, 4, 4, 2, 4, 2, 2, 1};
        const int cls = ((iz & 1) << 2) | ((iy & 1) << 1) | (ix & 1);
        j0 = pf[cls] * NSPL;
        j1 = j0 + tc[cls] * NSPL;
        constexpr int U = POS / 2;
        upos = ((size_t)(iz >> 1) * U + (iy >> 1)) * U + (ix >> 1);
      } else {
        j0 = 0;
        j1 = NSPL;
        upos = ((size_t)iz * POS + iy) * POS + ix;
      }
      const float* base = Pp + upos * COUT + co;
      for (int j = j0; j < j1; j++) {
        float4 v = *(const float4*)(base + (size_t)j * U3 * COUT);
        s.x += v.x; s.y += v.y; s.z += v.z; s.w += v.w;
      }
    }
    half4v h;
    h[0] = (_Float16)fmaxf(s.x, 0.f);
    h[1] = (_Float16)fmaxf(s.y, 0.f);
    h[2] = (_Float16)fmaxf(s.z, 0.f);
    h[3] = (_Float16)fmaxf(s.w, 0.f);
    *(half4v*)(P + (size_t)idx * 4) = h;
  }
}

__global__ __launch_bounds__(256, 2) void mega_k(
    const float* __restrict__ x, const float* __restrict__ w1,
    const float* __restrict__ w2, const float* __restrict__ w3,
    const float* __restrict__ w4, const float* __restrict__ w5,
    const float* __restrict__ w6, float* __restrict__ out,
    float* __restrict__ ws) {
  __shared__ SMem sm;
  unsigned* bar = (unsigned*)ws;
  unsigned* gen = (unsigned*)ws + 32;
  float* Q1 = ws + 64;                       // 216*64*512   = 7077888
  float* Q2 = Q1 + 7077888;                  // 24*512*256   = 3145728
  float* Q3 = Q2 + 3145728;                  // 54*512*128   = 3538944
  float* Q4 = Q3 + 3538944;                  // 12*4096*64   = 3145728
  _Float16* P1 = (_Float16*)(Q4 + 3145728);  // 5^3 *1024 = 128000
  _Float16* P2 = P1 + 128000;                // 10^3*512  = 512000
  _Float16* P3 = P2 + 512000;                // 9^3 *256  = 186624
  _Float16* P4 = P3 + 186624;                // 18^3*128  = 746496
  _Float16* P5 = P4 + 746496;                // 17^3*64   = 314432
  _Float16* P6 = P5 + 314432;                // 34^3*32   = 1257728

  const int gtid = blockIdx.x * 256 + threadIdx.x;

  // S0: pad x -> P1 (channels-last, left-pad 1) and zero all of P6
  for (int idx = gtid; idx < 125 * 1024; idx += GRID * 256) {
    int c = idx & 1023;
    int r = idx >> 10;
    int px = r % 5, py = (r / 5) % 5, pz = r / 25;
    float v = 0.f;
    if (px >= 1 && py >= 1 && pz >= 1)
      v = x[c * 64 + (pz - 1) * 16 + (py - 1) * 4 + (px - 1)];
    P1[idx] = (_Float16)v;
  }
  {
    half8 z = {};
    for (int idx = gtid; idx < 157216; idx += GRID * 256)
      *(half8*)(P6 + (size_t)idx * 8) = z;
  }
  grid_sync(bar, gen);

  // S1: conv1 1024->512, 4^3->8^3, s2; tiles (27,8,8) = 1728
  for (int vt = blockIdx.x; vt < 1728; vt += GRID)
    conv_tile<128, 1024, 512, 64, 4, 4, 5, 1, 0, 3>(
        vt % 27, (vt / 27) & 7, vt / 216, P1, w1, Q1, sm.c.A, sm.c.B);
  grid_sync(bar, gen);

  // S2: red1 -> P2 (10^3 x 512)
  red_stage<8, 512, 1, 8, 10>(Q1, P2);
  grid_sync(bar, gen);

  // S3: conv2 512->256, 8^3, s1; tiles (4,4,24) = 384
  for (int vt = blockIdx.x; vt < 384; vt += GRID)
    conv_tile<64, 512, 256, 64, 8, 8, 10, 0, 9, 3>(
        vt & 3, (vt / 4) & 3, vt / 16, P2, w2, Q2, sm.c.A, sm.c.B);
  grid_sync(bar, gen);

  // S4: red2 -> P3 (9^3 x 256)
  red_stage<8, 256, 0, 24, 9>(Q2, P3);
  grid_sync(bar, gen);

  // S5: conv3 256->128, 8^3->16^3, s2; tiles (108,2,2) = 432
  for (int vt = blockIdx.x; vt < 432; vt += GRID)
    conv_tile<128, 256, 128, 64, 8, 8, 9, 1, 0, 3>(
        vt % 108, (vt / 108) & 1, vt / 216, P3, w3, Q3, sm.c.A, sm.c.B);
  grid_sync(bar, gen);

  // S6: red3 -> P4 (18^3 x 128)
  red_stage<16, 128, 1, 2, 18>(Q3, P4);
  grid_sync(bar, gen);

  // S7: conv4 128->64, 16^3, s1; tiles (32,1,12) = 384
  for (int vt = blockIdx.x; vt < 384; vt += GRID)
    conv_tile<32, 128, 64, 64, 8, 16, 18, 0, 9, 3>(
        vt & 31, 0, vt / 32, P4, w4, Q4, sm.c.A, sm.c.B);
  grid_sync(bar, gen);

  // S8: red4 -> P5 (17^3 x 64)
  red_stage<16, 64, 0, 12, 17>(Q4, P5);
  grid_sync(bar, gen);

  // S9: conv5 64->32, 16^3->32^3, s2 class-loop, fp16 ReLU -> padded P6
  for (int vt = blockIdx.x; vt < 256; vt += GRID)
    conv_tile<64, 64, 32, 32, 8, 16, 17, 2, 0, 2>(
        vt, 0, 0, P5, w5, P6, sm.c.A, sm.c.B);
  grid_sync(bar, gen);

  // S10: conv6 32->1, 32^3 (no ReLU)
  for (int i = threadIdx.x; i < 864; i += 256) sm.w6[i] = w6[i];
  __syncthreads();
  for (int idx = gtid; idx < 32768; idx += GRID * 256) {
    int xx = idx & 31, yy = (idx >> 5) & 31, zz = idx >> 10;
    float a = 0.f;
    for (int dz = 0; dz < 3; dz++)
      for (int dy = 0; dy < 3; dy++)
        for (int dx = 0; dx < 3; dx++) {
          const _Float16* p =
              P6 + (size_t)(((zz + dz) * 34 + (yy + dy)) * 34 + (xx + dx)) * 32;
          const float* ww = &sm.w6[((dz * 3 + dy) * 3 + dx) * 32];
#pragma unroll
          for (int c = 0; c < 32; c += 8) {
            half8 pv = *(const half8*)&p[c];
#pragma unroll
            for (int u = 0; u < 8; u++) a += (float)pv[u] * ww[c + u];
          }
        }
    out[idx] = a;
  }
}

extern "C" void kernel_launch(void* const* d_in, const int* in_sizes, int n_in,
                              void* d_out, int out_size, void* d_ws,
                              size_t ws_size, hipStream_t stream) {
  const float* x  = (const float*)d_in[0];
  const float* w1 = (const float*)d_in[1];
  const float* w2 = (const float*)d_in[2];
  const float* w3 = (const float*)d_in[3];
  const float* w4 = (const float*)d_in[4];
  const float* w5 = (const float*)d_in[5];
  const float* w6 = (const float*)d_in[6];

  // zero the barrier state (first 256 B of ws)
  hipMemsetAsync(d_ws, 0, 256, stream);
  mega_k<<<GRID, 256, 0, stream>>>(x, w1, w2, w3, w4, w5, w6, (float*)d_out,
                                   (float*)d_ws);

  (void)in_sizes; (void)n_in; (void)out_size; (void)ws_size;
}